// Round 1
// 230.283 us; speedup vs baseline: 1.0101x; 1.0101x over previous
//
#include <hip/hip_runtime.h>
#include <math.h>

// 1D grayscale dilation (max-plus conv), K=11, halo=5, fp32.
// out[i] = max_j ( x[i-5+j] + h[j] ),  h[j] = -(j-5)^2 / (4*scale)
//
// R1: thread-contiguous coarsening breaks coalescing.
// R2/R3: register-reuse structures get serialized by the register minimizer.
// R4 (LDS tile, 81.7us): nothing >40% busy -> latency-bound on the
//   load -> barrier(vmcnt0 drain) -> LDS round-trip -> compute chain.
// R5 (this): wave-local halo via ds_bpermute. Halo is only +/-2 quads, so
//   each lane loads ONE float4 and gets the 10 cross-lane floats it needs
//   via __shfl_up/__shfl_down (10 bpermutes per quad vs 96B LDS r/w traffic).
//   No __shared__, no __syncthreads, no block-wide vmcnt drain. Wave covers
//   60 output quads per 64 loads (6.7% redundant reads, L2/L3-absorbed).
//   QPT=4 independent loads issued up-front per wave -> 4 in flight.

#define BLOCK   256
#define WPB     (BLOCK / 64)   // waves per block
#define QPT     4              // tiles (output groups) per wave
#define TQ      60             // output quads per tile (64 lanes - 4 halo)

__global__ __launch_bounds__(BLOCK) void dilate1d_kernel(
    const float4* __restrict__ x4,
    const float*  __restrict__ scale_p,
    float4*       __restrict__ out4,
    int n4,       // number of float4 elements in x / out
    int ntiles)   // ceil(n4 / TQ)
{
    const int lane = threadIdx.x & 63;
    const int wid  = blockIdx.x * WPB + (threadIdx.x >> 6);
    const int tau0 = wid * QPT;                  // first tile of this wave
    if (tau0 >= ntiles) return;                  // wave-uniform

    const float  NEG  = -INFINITY;
    const float4 NEG4 = make_float4(NEG, NEG, NEG, NEG);

    // ---- issue all loads up-front; no consumer until the shuffles ----
    // tile t loads quad g = (tau0+t)*TQ - 2 + lane; lane l's OWN quad is its
    // output quad; lanes 0,1,62,63 are halo-only.
    float4 v[QPT];
    const int gbase = tau0 * TQ - 2 + lane;
    const bool interior = (tau0 > 0) && (tau0 + QPT <= ntiles) &&
                          ((tau0 + QPT - 1) * TQ + 62 <= n4);
    if (interior) {
#pragma unroll
        for (int t = 0; t < QPT; ++t)
            v[t] = x4[gbase + t * TQ];
    } else {
        // only the first and last couple of waves take this path
#pragma unroll
        for (int t = 0; t < QPT; ++t) {
            int g = gbase + t * TQ;
            v[t] = ((tau0 + t) < ntiles && g >= 0 && g < n4) ? x4[g] : NEG4;
        }
    }

    // ---- structuring element: hp[d] = -d^2/(4s) ----
    const float r4s = 1.0f / (4.0f * scale_p[0]);
    const float hp1 = -1.0f  * r4s;
    const float hp2 = -4.0f  * r4s;
    const float hp3 = -9.0f  * r4s;
    const float hp4 = -16.0f * r4s;
    const float hp5 = -25.0f * r4s;

    const bool storelane = (lane >= 2) && (lane < 62);

#pragma unroll
    for (int t = 0; t < QPT; ++t) {
        const int tau = tau0 + t;
        if (tau >= ntiles) break;                // wave-uniform
        const float4 c = v[t];

        // w[k] = x[4*q - 5 + k], k = 0..13  (window for the 4 outputs of q)
        // own quad supplies w[5..8]; 10 floats come from lanes +/-1, +/-2.
        float w[14];
        w[0]  = __shfl_up(c.w, 2);
        w[1]  = __shfl_up(c.x, 1);
        w[2]  = __shfl_up(c.y, 1);
        w[3]  = __shfl_up(c.z, 1);
        w[4]  = __shfl_up(c.w, 1);
        w[5]  = c.x;  w[6] = c.y;  w[7] = c.z;  w[8] = c.w;
        w[9]  = __shfl_down(c.x, 1);
        w[10] = __shfl_down(c.y, 1);
        w[11] = __shfl_down(c.z, 1);
        w[12] = __shfl_down(c.w, 1);
        w[13] = __shfl_down(c.x, 2);

        float4 o;
        float* op = &o.x;
#pragma unroll
        for (int i = 0; i < 4; ++i) {            // static indices after unroll
            const int cc = 5 + i;
            float m = w[cc];                     // hp[0] == 0
            m = fmaxf(m, hp1 + fmaxf(w[cc - 1], w[cc + 1]));
            m = fmaxf(m, hp2 + fmaxf(w[cc - 2], w[cc + 2]));
            m = fmaxf(m, hp3 + fmaxf(w[cc - 3], w[cc + 3]));
            m = fmaxf(m, hp4 + fmaxf(w[cc - 4], w[cc + 4]));
            m = fmaxf(m, hp5 + fmaxf(w[cc - 5], w[cc + 5]));
            op[i] = m;
        }

        const int q = tau * TQ + (lane - 2);     // == gbase + t*TQ for this lane
        if (storelane && q < n4) out4[q] = o;
    }
}

extern "C" void kernel_launch(void* const* d_in, const int* in_sizes, int n_in,
                              void* d_out, int out_size, void* d_ws, size_t ws_size,
                              hipStream_t stream) {
    const float* x       = (const float*)d_in[0];
    const float* scale_p = (const float*)d_in[1];
    float*       out     = (float*)d_out;

    int n      = in_sizes[0];
    int n4     = n / 4;                          // n = 2^25 -> n4 = 2^23
    int ntiles = (n4 + TQ - 1) / TQ;             // 139811
    int waves  = (ntiles + QPT - 1) / QPT;       // 34953
    int blocks = (waves + WPB - 1) / WPB;        // 8739

    dilate1d_kernel<<<blocks, BLOCK, 0, stream>>>(
        (const float4*)x, scale_p, (float4*)out, n4, ntiles);
}